// Round 10
// baseline (121.389 us; speedup 1.0000x reference)
//
#include <hip/hip_runtime.h>
#include <math.h>

#define B 8
#define N_TOK 3137
#define D 256
#define H 8
#define DH 32
#define NX 56
#define M_SR 784     // 28*28
#define M_TOK 785    // 1 cls + 784
#define MP 832       // padded token count (13 * 64)
// dh^-0.5 * log2(e): exp(s) = exp2(s * log2e), folded into Q scale
#define QSCALE 0.25503486f
#define EPS 1e-5f

typedef __attribute__((ext_vector_type(8))) short short8;
typedef __attribute__((ext_vector_type(4))) float f32x4;

#if __has_builtin(__builtin_amdgcn_exp2f)
#define EXP2(x) __builtin_amdgcn_exp2f(x)
#else
#define EXP2(x) exp2f(x)
#endif

static __device__ __forceinline__ unsigned short f2bf(float f) {
    unsigned int u = __float_as_uint(f);
    u += 0x7fffu + ((u >> 16) & 1u);
    return (unsigned short)(u >> 16);
}

// async global->LDS 16B (m97 ladder step-3 pattern; vmcnt drained by barrier)
static __device__ __forceinline__ void gload16(const unsigned short* g, unsigned short* l) {
    __builtin_amdgcn_global_load_lds(
        (const __attribute__((address_space(1))) unsigned int*)g,
        (__attribute__((address_space(3))) unsigned int*)l,
        16, 0, 0);
}

// ---------------------------------------------------------------------------
// Fused prep: x->bf16, 4 weight transposes, K/V pad zeroing. One launch.
__global__ void prep_kernel(const float* __restrict__ x, const float* __restrict__ Wq,
                            const float* __restrict__ Wkv, const float* __restrict__ cw,
                            const float* __restrict__ Wproj,
                            unsigned short* __restrict__ xb, unsigned short* __restrict__ Wqt,
                            unsigned short* __restrict__ Wkvt, unsigned short* __restrict__ W2t,
                            unsigned short* __restrict__ Wpt,
                            unsigned short* __restrict__ Kbf, unsigned short* __restrict__ Vtb) {
    int bid = blockIdx.x, tid = threadIdx.x;
    if (bid < 6274) {                       // x fp32 -> bf16, float4-vectorized
        int idx = bid * 256 + tid;
        float4 v = ((const float4*)x)[idx];
        ushort4 o; o.x = f2bf(v.x); o.y = f2bf(v.y); o.z = f2bf(v.z); o.w = f2bf(v.w);
        ((ushort4*)xb)[idx] = o;
    } else if (bid < 6530) {                // Wq [256][256] -> Wqt [n][k]
        int idx = (bid - 6274) * 256 + tid;
        int n = idx & 255, k = idx >> 8;
        Wqt[n * 256 + k] = f2bf(Wq[idx]);
    } else if (bid < 7042) {                // Wkv [256][512] -> Wkvt [n][k]
        int idx = (bid - 6530) * 256 + tid;
        int n = idx & 511, k = idx >> 9;
        Wkvt[(size_t)n * 256 + k] = f2bf(Wkv[idx]);
    } else if (bid < 8066) {                // conv_w [O][I][2][2] -> W2t [o][q*256+i]
        int idx = (bid - 7042) * 256 + tid;
        int o = idx >> 10, k = idx & 1023;
        int q = k >> 8, i = k & 255;
        W2t[idx] = f2bf(cw[((size_t)o << 10) + (i << 2) + q]);
    } else if (bid < 8322) {                // Wproj -> Wpt
        int idx = (bid - 8066) * 256 + tid;
        int n = idx & 255, k = idx >> 8;
        Wpt[n * 256 + k] = f2bf(Wproj[idx]);
    } else {                                // zero pad rows m=785..831 of Kbf, Vtb
        int idx = (bid - 8322) * 256 + tid;
        if (idx < 96256) {
            int d = idx & 31; int rest = idx >> 5;
            int m = M_TOK + rest % 47; int bh = rest / 47;
            Kbf[((size_t)bh * MP + m) * 32 + d] = 0;
        } else if (idx < 192512) {
            int i2 = idx - 96256;
            int j = i2 % 47; int rest = i2 / 47;
            int d = rest & 31; int bh = rest >> 5;
            Vtb[((size_t)bh * 32 + d) * MP + M_TOK + j] = 0;
        }
    }
}

// ---------------------------------------------------------------------------
// bf16 MFMA GEMM: C[M][N] = A[M][KTOT] x Bt[N][KTOT]^T, fused epilogues.
// BK=128 K-chunks: 16KB+16KB LDS -> 5 blocks/CU. Staging via global_load_lds
// width-16: linear LDS dest, inverse-swizzled per-lane global source.
enum EpiMode { EPI_Q, EPI_XR, EPI_KV, EPI_OUT };
enum AMode { A_PLAIN, A_CONV };

template<int KTOT, AMode AM, EpiMode EM>
__global__ __launch_bounds__(256) void mfma_gemm_kernel(
        const unsigned short* __restrict__ A,
        const unsigned short* __restrict__ Bt,
        void* __restrict__ Cout,
        const float* __restrict__ bias,
        int Mrows) {
    __shared__ __align__(16) unsigned short Alds[64 * 128];
    __shared__ __align__(16) unsigned short Blds[64 * 128];
    const int tid = threadIdx.x;
    const int lane = tid & 63, wave = tid >> 6;
    const int l16 = lane & 15, lhi = lane >> 4;
    const int row0 = blockIdx.x * 64;
    const int col0 = blockIdx.y * 64;
    const int wr = (wave >> 1) * 32, wc = (wave & 1) * 32;

    f32x4 acc[2][2];
    #pragma unroll
    for (int mi = 0; mi < 2; mi++)
        #pragma unroll
        for (int ni = 0; ni < 2; ni++)
            acc[mi][ni] = (f32x4){0.f, 0.f, 0.f, 0.f};

    for (int kc = 0; kc < KTOT / 128; kc++) {
        __syncthreads();
        // stage A: linear LDS dest (r,p), fetch logical slot s = p ^ (r&7)
        #pragma unroll
        for (int j = 0; j < 4; j++) {
            int sl = j * 256 + tid;
            int r = sl >> 4, p = sl & 15;
            int s = p ^ (r & 7);
            const unsigned short* gp;
            if (AM == A_PLAIN) {
                gp = A + ((size_t)(row0 + r) * KTOT + kc * 128 + s * 8);
            } else {
                // conv gather: global k = kc*128 + s*8; q = kc>>1, ioff = (kc&1)*128+s*8
                int grow = row0 + r;
                int b = grow / 784, pp = grow - b * 784;
                int oy = pp / 28, ox = pp - oy * 28;
                int q = kc >> 1;
                int kh = q >> 1, kw = q & 1;
                int tok = 1 + (2 * oy + kh) * NX + (2 * ox + kw);
                gp = A + ((size_t)(b * N_TOK + tok) * 256 + (kc & 1) * 128 + s * 8);
            }
            gload16(gp, &Alds[r * 128 + p * 8]);
        }
        // stage Bt (rows col0..col0+63 always in-bounds)
        #pragma unroll
        for (int j = 0; j < 4; j++) {
            int sl = j * 256 + tid;
            int r = sl >> 4, p = sl & 15;
            int s = p ^ (r & 7);
            gload16(Bt + ((size_t)(col0 + r) * KTOT + kc * 128 + s * 8),
                    &Blds[r * 128 + p * 8]);
        }
        __syncthreads();
        #pragma unroll
        for (int ks = 0; ks < 4; ks++) {
            short8 af[2], bfr[2];
            #pragma unroll
            for (int mi = 0; mi < 2; mi++) {
                int r = wr + mi * 16 + l16;
                int s = ks * 4 + lhi;
                af[mi] = *reinterpret_cast<const short8*>(Alds + r * 128 + ((s ^ (r & 7)) * 8));
            }
            #pragma unroll
            for (int ni = 0; ni < 2; ni++) {
                int r = wc + ni * 16 + l16;
                int s = ks * 4 + lhi;
                bfr[ni] = *reinterpret_cast<const short8*>(Blds + r * 128 + ((s ^ (r & 7)) * 8));
            }
            #pragma unroll
            for (int mi = 0; mi < 2; mi++)
                #pragma unroll
                for (int ni = 0; ni < 2; ni++)
                    acc[mi][ni] = __builtin_amdgcn_mfma_f32_16x16x32_bf16(af[mi], bfr[ni], acc[mi][ni], 0, 0, 0);
        }
    }

    #pragma unroll
    for (int mi = 0; mi < 2; mi++) {
        #pragma unroll
        for (int ni = 0; ni < 2; ni++) {
            #pragma unroll
            for (int r = 0; r < 4; r++) {
                int grow = row0 + wr + mi * 16 + lhi * 4 + r;
                int gcol = col0 + wc + ni * 16 + l16;
                float v = acc[mi][ni][r];
                if (EM == EPI_Q) {
                    if (grow < Mrows) {
                        int b = grow / N_TOK, n = grow - b * N_TOK;
                        int h = gcol >> 5, d = gcol & 31;
                        ((unsigned short*)Cout)[(((size_t)(b * 8 + h) * N_TOK + n) * 32) + d] = f2bf(v * QSCALE);
                    }
                } else if (EM == EPI_XR) {
                    int b = grow / 784, p = grow - b * 784;
                    ((float*)Cout)[((size_t)(b * M_TOK) + 1 + p) * 256 + gcol] = v;
                } else if (EM == EPI_KV) {
                    if (grow < Mrows) {
                        int b = grow / M_TOK, m = grow - b * M_TOK;
                        if (gcol < 256) {
                            int h = gcol >> 5, d = gcol & 31;
                            ((unsigned short*)Cout)[((size_t)(b * 8 + h) * MP + m) * 32 + d] = f2bf(v);
                        } else {
                            int c = gcol - 256;
                            int h = c >> 5, d = c & 31;
                            ((unsigned short*)Cout)[(size_t)64 * MP * 32 + ((size_t)(b * 8 + h) * 32 + d) * MP + m] = f2bf(v);
                        }
                    }
                } else { // EPI_OUT
                    if (grow < Mrows)
                        ((float*)Cout)[(size_t)grow * 256 + gcol] = v + bias[gcol];
                }
            }
        }
    }
}

// ---------------------------------------------------------------------------
// Instance-norm (deterministic 3-stage) on fp32 XRf, rows 1..784
__global__ void stats_partial_kernel(const float* __restrict__ XR,
                                     float* __restrict__ psum, float* __restrict__ psq) {
    int b = blockIdx.x / 28, pg = blockIdx.x % 28;
    int c = threadIdx.x;
    float s = 0.f, s2 = 0.f;
    for (int pp = 0; pp < 28; pp++) {
        int p = pg * 28 + pp;
        float v = XR[((size_t)b * M_TOK + 1 + p) * D + c];
        s += v; s2 += v * v;
    }
    psum[(size_t)(b * 28 + pg) * D + c] = s;
    psq [(size_t)(b * 28 + pg) * D + c] = s2;
}

__global__ void stats_final_kernel(const float* __restrict__ psum, const float* __restrict__ psq,
                                   float* __restrict__ mean, float* __restrict__ rstd) {
    int b = blockIdx.x, c = threadIdx.x;
    float s = 0.f, s2 = 0.f;
    for (int pg = 0; pg < 28; pg++) {
        s  += psum[(size_t)(b * 28 + pg) * D + c];
        s2 += psq [(size_t)(b * 28 + pg) * D + c];
    }
    float mu = s * (1.f / 784.f);
    float var = s2 * (1.f / 784.f) - mu * mu;
    mean[b * D + c] = mu;
    rstd[b * D + c] = rsqrtf(var + EPS);
}

// normalize rows 1..784 -> XRb bf16; blocks >= 6272 copy the cls row from xb
__global__ void normalize_kernel(const float* __restrict__ mean, const float* __restrict__ rstd,
                                 const float* __restrict__ XRf, unsigned short* __restrict__ XRb,
                                 const unsigned short* __restrict__ xb) {
    int bid = blockIdx.x;
    if (bid < 6272) {
        int idx = bid * 256 + threadIdx.x;
        int c = idx & 255;
        int bp = idx >> 8;
        int b = bp / 784, p = bp - b * 784;
        size_t off = ((size_t)b * M_TOK + 1 + p) * 256 + c;
        XRb[off] = f2bf((XRf[off] - mean[b * 256 + c]) * rstd[b * 256 + c]);
    } else {
        int b = bid - 6272, c = threadIdx.x;
        XRb[(size_t)b * M_TOK * 256 + c] = xb[(size_t)b * N_TOK * 256 + c];
    }
}

// ---------------------------------------------------------------------------
// Swapped-operand MFMA flash attention, r9-proven QI=2 structure with K/V
// LDS double-buffering (T14 async-STAGE): issue tile t+1 global loads before
// the barrier, compute tile t, write t+1 regs to LDS[buf^1] after compute.
// Hazards: write buf^1 (end of iter t) vs read buf^1 (iter t+1) separated by
// the iter-t+1 barrier; read buf (iter t) vs write buf (end of iter t+1)
// separated by... iter t+1's barrier precedes its write. One barrier/iter.
// Math, masking, swizzles, epilogue byte-identical to r9.
__global__ __launch_bounds__(256) void attn_mfma_kernel(
        const unsigned short* __restrict__ Qbf,
        const unsigned short* __restrict__ Kbf,
        const unsigned short* __restrict__ Vt,
        unsigned short* __restrict__ AObf) {
    __shared__ __align__(16) unsigned short Klds[2][64 * 32];
    __shared__ __align__(16) unsigned short Vlds[2][32 * 64];
    const int tid = threadIdx.x;
    const int lane = tid & 63, wave = tid >> 6;
    const int l16 = lane & 15, lhi = lane >> 4;
    const int b = blockIdx.z, h = blockIdx.y, bh = b * 8 + h;
    const int q0 = blockIdx.x * 128 + wave * 32;

    short8 qf[2];
    #pragma unroll
    for (int qi = 0; qi < 2; qi++) {
        qf[qi] = (short8){0, 0, 0, 0, 0, 0, 0, 0};
        int qrow = q0 + qi * 16 + l16;
        if (qrow < N_TOK)
            qf[qi] = *reinterpret_cast<const short8*>(Qbf + ((size_t)bh * N_TOK + qrow) * 32 + lhi * 8);
    }

    f32x4 o0[2], o1[2];
    float lsum[2];
    #pragma unroll
    for (int qi = 0; qi < 2; qi++) {
        o0[qi] = (f32x4){0.f, 0.f, 0.f, 0.f};
        o1[qi] = (f32x4){0.f, 0.f, 0.f, 0.f};
        lsum[qi] = 0.f;
    }

    // K staging: pre-swizzled global source, linear LDS dest
    const int krow = tid >> 2, kcp = tid & 3;
    const int kclog = kcp ^ ((krow >> 1) & 3);
    const unsigned short* kg = Kbf + ((size_t)bh * MP + krow) * 32 + kclog * 8;
    const int kloff = tid * 8;
    // V staging: linear global read, permuted+swizzled LDS scatter (2x b64)
    const int vrow = tid >> 3, vc = tid & 7;
    const int vh = vc >> 2, c2 = vc & 3;
    const unsigned short* vg = Vt + ((size_t)bh * 32 + vrow) * MP + vc * 8;
    const int slotA = vh * 4 + 2 * (c2 & 1);
    const int hoff = (c2 >> 1) * 4;   // ushort offset within 16B slot
    const int v0off = vrow * 64 + ((slotA ^ (vrow & 7)) * 8) + hoff;
    const int v1off = vrow * 64 + (((slotA + 1) ^ (vrow & 7)) * 8) + hoff;

    // prologue: stage tile 0 into buffer 0
    {
        uint4 kd = *reinterpret_cast<const uint4*>(kg);
        uint4 vd = *reinterpret_cast<const uint4*>(vg);
        *reinterpret_cast<uint4*>(&Klds[0][kloff]) = kd;
        *reinterpret_cast<uint2*>(&Vlds[0][v0off]) = make_uint2(vd.x, vd.y);
        *reinterpret_cast<uint2*>(&Vlds[0][v1off]) = make_uint2(vd.z, vd.w);
    }
    int buf = 0;
    for (int t0 = 0; t0 < MP; t0 += 64) {
        const bool more = (t0 + 64 < MP);
        uint4 kn = {0, 0, 0, 0}, vn = {0, 0, 0, 0};
        if (more) {
            kn = *reinterpret_cast<const uint4*>(kg + (size_t)(t0 + 64) * 32);
            vn = *reinterpret_cast<const uint4*>(vg + (t0 + 64));
        }
        __syncthreads();
        const unsigned short* Kb = Klds[buf];
        const unsigned short* Vb = Vlds[buf];
        const bool last = (t0 + 64 > M_TOK);
        #pragma unroll
        for (int hh = 0; hh < 2; hh++) {
            int tre = hh * 32 + l16;
            int tro = hh * 32 + 16 + l16;
            short8 kfe = *reinterpret_cast<const short8*>(
                Kb + tre * 32 + ((lhi ^ ((tre >> 1) & 3)) * 8));
            short8 kfo = *reinterpret_cast<const short8*>(
                Kb + tro * 32 + ((lhi ^ ((tro >> 1) & 3)) * 8));
            int rv0 = l16, rv1 = 16 + l16;
            short8 vf0 = *reinterpret_cast<const short8*>(
                Vb + rv0 * 64 + (((hh * 4 + lhi) ^ (rv0 & 7)) * 8));
            short8 vf1 = *reinterpret_cast<const short8*>(
                Vb + rv1 * 64 + (((hh * 4 + lhi) ^ (rv1 & 7)) * 8));
            #pragma unroll
            for (int qi = 0; qi < 2; qi++) {
                f32x4 Se = __builtin_amdgcn_mfma_f32_16x16x32_bf16(
                    kfe, qf[qi], (f32x4){0.f, 0.f, 0.f, 0.f}, 0, 0, 0);
                f32x4 So = __builtin_amdgcn_mfma_f32_16x16x32_bf16(
                    kfo, qf[qi], (f32x4){0.f, 0.f, 0.f, 0.f}, 0, 0, 0);
                float ee0 = EXP2(Se[0]), ee1 = EXP2(Se[1]), ee2 = EXP2(Se[2]), ee3 = EXP2(Se[3]);
                float eo0 = EXP2(So[0]), eo1 = EXP2(So[1]), eo2 = EXP2(So[2]), eo3 = EXP2(So[3]);
                if (!last) {
                    lsum[qi] += ((ee0 + ee1) + (ee2 + ee3)) + ((eo0 + eo1) + (eo2 + eo3));
                } else if (hh == 0) {
                    // even-sub tokens 768+lhi*4+r all valid; odd-sub only token 784
                    lsum[qi] += (ee0 + ee1) + (ee2 + ee3);
                    if (lhi == 0) lsum[qi] += eo0;
                }
                union { short8 s; unsigned int u[4]; } pf;
                asm("v_cvt_pk_bf16_f32 %0, %1, %2" : "=v"(pf.u[0]) : "v"(ee0), "v"(ee1));
                asm("v_cvt_pk_bf16_f32 %0, %1, %2" : "=v"(pf.u[1]) : "v"(ee2), "v"(ee3));
                asm("v_cvt_pk_bf16_f32 %0, %1, %2" : "=v"(pf.u[2]) : "v"(eo0), "v"(eo1));
                asm("v_cvt_pk_bf16_f32 %0, %1, %2" : "=v"(pf.u[3]) : "v"(eo2), "v"(eo3));
                o0[qi] = __builtin_amdgcn_mfma_f32_16x16x32_bf16(pf.s, vf0, o0[qi], 0, 0, 0);
                o1[qi] = __builtin_amdgcn_mfma_f32_16x16x32_bf16(pf.s, vf1, o1[qi], 0, 0, 0);
            }
        }
        if (more) {
            *reinterpret_cast<uint4*>(&Klds[buf ^ 1][kloff]) = kn;
            *reinterpret_cast<uint2*>(&Vlds[buf ^ 1][v0off]) = make_uint2(vn.x, vn.y);
            *reinterpret_cast<uint2*>(&Vlds[buf ^ 1][v1off]) = make_uint2(vn.z, vn.w);
            buf ^= 1;
        }
    }
    // total row-sum: reduce across lhi groups; lane l16=r holds row r's total
    #pragma unroll
    for (int qi = 0; qi < 2; qi++) {
        lsum[qi] += __shfl_xor(lsum[qi], 16);
        lsum[qi] += __shfl_xor(lsum[qi], 32);
    }
    #pragma unroll
    for (int qi = 0; qi < 2; qi++) {
        #pragma unroll
        for (int r = 0; r < 4; r++) {
            int qrw = lhi * 4 + r;
            float inv = 1.f / __shfl(lsum[qi], qrw);   // unconditional, r4-style
            int row = q0 + qi * 16 + qrw;
            if (row < N_TOK) {
                unsigned short* op = AObf + ((size_t)(b * N_TOK + row)) * 256 + h * 32;
                op[l16]      = f2bf(o0[qi][r] * inv);
                op[16 + l16] = f2bf(o1[qi][r] * inv);
            }
        }
    }
}

// ---------------------------------------------------------------------------
extern "C" void kernel_launch(void* const* d_in, const int* in_sizes, int n_in,
                              void* d_out, int out_size, void* d_ws, size_t ws_size,
                              hipStream_t stream) {
    const float* x      = (const float*)d_in[0];
    const float* Wq     = (const float*)d_in[1];
    const float* Wkv    = (const float*)d_in[2];
    const float* conv_w = (const float*)d_in[3];
    const float* Wproj  = (const float*)d_in[4];
    const float* bproj  = (const float*)d_in[5];
    float* out = (float*)d_out;

    unsigned short* us   = (unsigned short*)d_ws;
    unsigned short* xb   = us;                     // 6424576
    unsigned short* AObf = us;                     // alias of xb (xb dead by attn)
    unsigned short* Qbf  = xb + 6424576;           // 6424576
    unsigned short* Kbf  = Qbf + 6424576;          // 1703936
    unsigned short* Vtb  = Kbf + 1703936;          // 1703936 (contiguous after Kbf)
    unsigned short* XRb  = Vtb + 1703936;          // 1607680
    unsigned short* Wqt  = XRb + 1607680;          // 65536
    unsigned short* Wkvt = Wqt + 65536;            // 131072
    unsigned short* W2t  = Wkvt + 131072;          // 262144
    unsigned short* Wpt  = W2t + 262144;           // 65536
    float* XRf  = (float*)(Wpt + 65536);           // 1607680 f
    float* psum = XRf + 1607680;                   // 57344
    float* psq  = psum + 57344;                    // 57344
    float* mean = psq + 57344;                     // 2048
    float* rstd = mean + 2048;                     // 2048

    prep_kernel<<<9075, 256, 0, stream>>>(x, Wq, Wkv, conv_w, Wproj,
                                          xb, Wqt, Wkvt, W2t, Wpt, Kbf, Vtb);
    mfma_gemm_kernel<256, A_PLAIN, EPI_Q><<<dim3(393, 4), 256, 0, stream>>>(
        xb, Wqt, Qbf, nullptr, B * N_TOK);
    mfma_gemm_kernel<1024, A_CONV, EPI_XR><<<dim3(98, 4), 256, 0, stream>>>(
        xb, W2t, XRf, nullptr, B * 784);
    stats_partial_kernel<<<B * 28, 256, 0, stream>>>(XRf, psum, psq);
    stats_final_kernel<<<B, 256, 0, stream>>>(psum, psq, mean, rstd);
    normalize_kernel<<<6280, 256, 0, stream>>>(mean, rstd, XRf, XRb, xb);
    mfma_gemm_kernel<256, A_PLAIN, EPI_KV><<<dim3(99, 8), 256, 0, stream>>>(
        XRb, Wkvt, Kbf, nullptr, B * M_TOK);
    attn_mfma_kernel<<<dim3(25, 8, 8), 256, 0, stream>>>(Qbf, Kbf, Vtb, AObf);
    mfma_gemm_kernel<256, A_PLAIN, EPI_OUT><<<dim3(393, 4), 256, 0, stream>>>(
        AObf, Wpt, out, bproj, B * N_TOK);
}

// Round 11
// 120.167 us; speedup vs baseline: 1.0102x; 1.0102x over previous
//
#include <hip/hip_runtime.h>
#include <math.h>

#define B 8
#define N_TOK 3137
#define D 256
#define H 8
#define DH 32
#define NX 56
#define M_SR 784     // 28*28
#define M_TOK 785    // 1 cls + 784
#define MP 832       // padded token count (13 * 64)
// dh^-0.5 * log2(e): exp(s) = exp2(s * log2e), folded into Q scale
#define QSCALE 0.25503486f
#define EPS 1e-5f

typedef __attribute__((ext_vector_type(8))) short short8;
typedef __attribute__((ext_vector_type(4))) float f32x4;

#if __has_builtin(__builtin_amdgcn_exp2f)
#define EXP2(x) __builtin_amdgcn_exp2f(x)
#else
#define EXP2(x) exp2f(x)
#endif

static __device__ __forceinline__ unsigned short f2bf(float f) {
    unsigned int u = __float_as_uint(f);
    u += 0x7fffu + ((u >> 16) & 1u);
    return (unsigned short)(u >> 16);
}

// async global->LDS 16B (m97 ladder step-3 pattern)
static __device__ __forceinline__ void gload16(const unsigned short* g, unsigned short* l) {
    __builtin_amdgcn_global_load_lds(
        (const __attribute__((address_space(1))) unsigned int*)g,
        (__attribute__((address_space(3))) unsigned int*)l,
        16, 0, 0);
}

// ---------------------------------------------------------------------------
// Fused prep: x->bf16, 4 weight transposes, K/V pad zeroing. One launch.
__global__ void prep_kernel(const float* __restrict__ x, const float* __restrict__ Wq,
                            const float* __restrict__ Wkv, const float* __restrict__ cw,
                            const float* __restrict__ Wproj,
                            unsigned short* __restrict__ xb, unsigned short* __restrict__ Wqt,
                            unsigned short* __restrict__ Wkvt, unsigned short* __restrict__ W2t,
                            unsigned short* __restrict__ Wpt,
                            unsigned short* __restrict__ Kbf, unsigned short* __restrict__ Vtb) {
    int bid = blockIdx.x, tid = threadIdx.x;
    if (bid < 6274) {                       // x fp32 -> bf16, float4-vectorized
        int idx = bid * 256 + tid;
        float4 v = ((const float4*)x)[idx];
        ushort4 o; o.x = f2bf(v.x); o.y = f2bf(v.y); o.z = f2bf(v.z); o.w = f2bf(v.w);
        ((ushort4*)xb)[idx] = o;
    } else if (bid < 6530) {                // Wq [256][256] -> Wqt [n][k]
        int idx = (bid - 6274) * 256 + tid;
        int n = idx & 255, k = idx >> 8;
        Wqt[n * 256 + k] = f2bf(Wq[idx]);
    } else if (bid < 7042) {                // Wkv [256][512] -> Wkvt [n][k]
        int idx = (bid - 6530) * 256 + tid;
        int n = idx & 511, k = idx >> 9;
        Wkvt[(size_t)n * 256 + k] = f2bf(Wkv[idx]);
    } else if (bid < 8066) {                // conv_w [O][I][2][2] -> W2t [o][q*256+i]
        int idx = (bid - 7042) * 256 + tid;
        int o = idx >> 10, k = idx & 1023;
        int q = k >> 8, i = k & 255;
        W2t[idx] = f2bf(cw[((size_t)o << 10) + (i << 2) + q]);
    } else if (bid < 8322) {                // Wproj -> Wpt
        int idx = (bid - 8066) * 256 + tid;
        int n = idx & 255, k = idx >> 8;
        Wpt[n * 256 + k] = f2bf(Wproj[idx]);
    } else {                                // zero pad rows m=785..831 of Kbf, Vtb
        int idx = (bid - 8322) * 256 + tid;
        if (idx < 96256) {
            int d = idx & 31; int rest = idx >> 5;
            int m = M_TOK + rest % 47; int bh = rest / 47;
            Kbf[((size_t)bh * MP + m) * 32 + d] = 0;
        } else if (idx < 192512) {
            int i2 = idx - 96256;
            int j = i2 % 47; int rest = i2 / 47;
            int d = rest & 31; int bh = rest >> 5;
            Vtb[((size_t)bh * 32 + d) * MP + M_TOK + j] = 0;
        }
    }
}

// ---------------------------------------------------------------------------
// bf16 MFMA GEMM: C[M][N] = A[M][KTOT] x Bt[N][KTOT]^T, fused epilogues.
// BK=128 K-chunks: 16KB+16KB LDS -> 5 blocks/CU. Staging via global_load_lds
// width-16: linear LDS dest, inverse-swizzled per-lane global source.
enum EpiMode { EPI_Q, EPI_XR, EPI_KV, EPI_OUT };
enum AMode { A_PLAIN, A_CONV };

template<int KTOT, AMode AM, EpiMode EM>
__global__ __launch_bounds__(256) void mfma_gemm_kernel(
        const unsigned short* __restrict__ A,
        const unsigned short* __restrict__ Bt,
        void* __restrict__ Cout,
        const float* __restrict__ bias,
        int Mrows) {
    __shared__ __align__(16) unsigned short Alds[64 * 128];
    __shared__ __align__(16) unsigned short Blds[64 * 128];
    const int tid = threadIdx.x;
    const int lane = tid & 63, wave = tid >> 6;
    const int l16 = lane & 15, lhi = lane >> 4;
    const int row0 = blockIdx.x * 64;
    const int col0 = blockIdx.y * 64;
    const int wr = (wave >> 1) * 32, wc = (wave & 1) * 32;

    f32x4 acc[2][2];
    #pragma unroll
    for (int mi = 0; mi < 2; mi++)
        #pragma unroll
        for (int ni = 0; ni < 2; ni++)
            acc[mi][ni] = (f32x4){0.f, 0.f, 0.f, 0.f};

    for (int kc = 0; kc < KTOT / 128; kc++) {
        __syncthreads();
        // stage A: linear LDS dest (r,p), fetch logical slot s = p ^ (r&7)
        #pragma unroll
        for (int j = 0; j < 4; j++) {
            int sl = j * 256 + tid;
            int r = sl >> 4, p = sl & 15;
            int s = p ^ (r & 7);
            const unsigned short* gp;
            if (AM == A_PLAIN) {
                gp = A + ((size_t)(row0 + r) * KTOT + kc * 128 + s * 8);
            } else {
                int grow = row0 + r;
                int b = grow / 784, pp = grow - b * 784;
                int oy = pp / 28, ox = pp - oy * 28;
                int q = kc >> 1;
                int kh = q >> 1, kw = q & 1;
                int tok = 1 + (2 * oy + kh) * NX + (2 * ox + kw);
                gp = A + ((size_t)(b * N_TOK + tok) * 256 + (kc & 1) * 128 + s * 8);
            }
            gload16(gp, &Alds[r * 128 + p * 8]);
        }
        // stage Bt (rows col0..col0+63 always in-bounds)
        #pragma unroll
        for (int j = 0; j < 4; j++) {
            int sl = j * 256 + tid;
            int r = sl >> 4, p = sl & 15;
            int s = p ^ (r & 7);
            gload16(Bt + ((size_t)(col0 + r) * KTOT + kc * 128 + s * 8),
                    &Blds[r * 128 + p * 8]);
        }
        __syncthreads();
        #pragma unroll
        for (int ks = 0; ks < 4; ks++) {
            short8 af[2], bfr[2];
            #pragma unroll
            for (int mi = 0; mi < 2; mi++) {
                int r = wr + mi * 16 + l16;
                int s = ks * 4 + lhi;
                af[mi] = *reinterpret_cast<const short8*>(Alds + r * 128 + ((s ^ (r & 7)) * 8));
            }
            #pragma unroll
            for (int ni = 0; ni < 2; ni++) {
                int r = wc + ni * 16 + l16;
                int s = ks * 4 + lhi;
                bfr[ni] = *reinterpret_cast<const short8*>(Blds + r * 128 + ((s ^ (r & 7)) * 8));
            }
            #pragma unroll
            for (int mi = 0; mi < 2; mi++)
                #pragma unroll
                for (int ni = 0; ni < 2; ni++)
                    acc[mi][ni] = __builtin_amdgcn_mfma_f32_16x16x32_bf16(af[mi], bfr[ni], acc[mi][ni], 0, 0, 0);
        }
    }

    #pragma unroll
    for (int mi = 0; mi < 2; mi++) {
        #pragma unroll
        for (int ni = 0; ni < 2; ni++) {
            #pragma unroll
            for (int r = 0; r < 4; r++) {
                int grow = row0 + wr + mi * 16 + lhi * 4 + r;
                int gcol = col0 + wc + ni * 16 + l16;
                float v = acc[mi][ni][r];
                if (EM == EPI_Q) {
                    if (grow < Mrows) {
                        int b = grow / N_TOK, n = grow - b * N_TOK;
                        int h = gcol >> 5, d = gcol & 31;
                        ((unsigned short*)Cout)[(((size_t)(b * 8 + h) * N_TOK + n) * 32) + d] = f2bf(v * QSCALE);
                    }
                } else if (EM == EPI_XR) {
                    int b = grow / 784, p = grow - b * 784;
                    ((float*)Cout)[((size_t)(b * M_TOK) + 1 + p) * 256 + gcol] = v;
                } else if (EM == EPI_KV) {
                    if (grow < Mrows) {
                        int b = grow / M_TOK, m = grow - b * M_TOK;
                        if (gcol < 256) {
                            int h = gcol >> 5, d = gcol & 31;
                            ((unsigned short*)Cout)[((size_t)(b * 8 + h) * MP + m) * 32 + d] = f2bf(v);
                        } else {
                            int c = gcol - 256;
                            int h = c >> 5, d = c & 31;
                            ((unsigned short*)Cout)[(size_t)64 * MP * 32 + ((size_t)(b * 8 + h) * 32 + d) * MP + m] = f2bf(v);
                        }
                    }
                } else { // EPI_OUT
                    if (grow < Mrows)
                        ((float*)Cout)[(size_t)grow * 256 + gcol] = v + bias[gcol];
                }
            }
        }
    }
}

// ---------------------------------------------------------------------------
// Instance-norm (deterministic 3-stage) on fp32 XRf, rows 1..784
__global__ void stats_partial_kernel(const float* __restrict__ XR,
                                     float* __restrict__ psum, float* __restrict__ psq) {
    int b = blockIdx.x / 28, pg = blockIdx.x % 28;
    int c = threadIdx.x;
    float s = 0.f, s2 = 0.f;
    for (int pp = 0; pp < 28; pp++) {
        int p = pg * 28 + pp;
        float v = XR[((size_t)b * M_TOK + 1 + p) * D + c];
        s += v; s2 += v * v;
    }
    psum[(size_t)(b * 28 + pg) * D + c] = s;
    psq [(size_t)(b * 28 + pg) * D + c] = s2;
}

__global__ void stats_final_kernel(const float* __restrict__ psum, const float* __restrict__ psq,
                                   float* __restrict__ mean, float* __restrict__ rstd) {
    int b = blockIdx.x, c = threadIdx.x;
    float s = 0.f, s2 = 0.f;
    for (int pg = 0; pg < 28; pg++) {
        s  += psum[(size_t)(b * 28 + pg) * D + c];
        s2 += psq [(size_t)(b * 28 + pg) * D + c];
    }
    float mu = s * (1.f / 784.f);
    float var = s2 * (1.f / 784.f) - mu * mu;
    mean[b * D + c] = mu;
    rstd[b * D + c] = rsqrtf(var + EPS);
}

// normalize rows 1..784 -> XRb bf16; blocks >= 6272 copy the cls row from xb
__global__ void normalize_kernel(const float* __restrict__ mean, const float* __restrict__ rstd,
                                 const float* __restrict__ XRf, unsigned short* __restrict__ XRb,
                                 const unsigned short* __restrict__ xb) {
    int bid = blockIdx.x;
    if (bid < 6272) {
        int idx = bid * 256 + threadIdx.x;
        int c = idx & 255;
        int bp = idx >> 8;
        int b = bp / 784, p = bp - b * 784;
        size_t off = ((size_t)b * M_TOK + 1 + p) * 256 + c;
        XRb[off] = f2bf((XRf[off] - mean[b * 256 + c]) * rstd[b * 256 + c]);
    } else {
        int b = bid - 6272, c = threadIdx.x;
        XRb[(size_t)b * M_TOK * 256 + c] = xb[(size_t)b * N_TOK * 256 + c];
    }
}

// ---------------------------------------------------------------------------
// Swapped-operand MFMA flash attention, r9 math + r10-proven dbuf dataflow,
// now with T3/T4 counted-wait raw-barrier schedule:
//   issue K-gload_lds + V-reg-load for t+1 -> compute tile t ->
//   vmcnt(0) (t+1 loads drained UNDER compute) -> write V ->
//   {lgkmcnt(0); s_barrier} as ONE memory-clobbered asm (no compiler vmcnt
//   drain before barrier; fences reordering both ways per rule #18).
// Hazards identical to r10 (passed): W(buf^1)@t vs R(buf^1)@t+1 split by the
// barrier; gload(buf^1)@t vs R(buf^1)@t-1 drained by t-1's lgkm+barrier.
__global__ __launch_bounds__(256) void attn_mfma_kernel(
        const unsigned short* __restrict__ Qbf,
        const unsigned short* __restrict__ Kbf,
        const unsigned short* __restrict__ Vt,
        unsigned short* __restrict__ AObf) {
    __shared__ __align__(16) unsigned short Klds[2][64 * 32];
    __shared__ __align__(16) unsigned short Vlds[2][32 * 64];
    const int tid = threadIdx.x;
    const int lane = tid & 63, wave = tid >> 6;
    const int l16 = lane & 15, lhi = lane >> 4;
    const int b = blockIdx.z, h = blockIdx.y, bh = b * 8 + h;
    const int q0 = blockIdx.x * 128 + wave * 32;

    short8 qf[2];
    #pragma unroll
    for (int qi = 0; qi < 2; qi++) {
        qf[qi] = (short8){0, 0, 0, 0, 0, 0, 0, 0};
        int qrow = q0 + qi * 16 + l16;
        if (qrow < N_TOK)
            qf[qi] = *reinterpret_cast<const short8*>(Qbf + ((size_t)bh * N_TOK + qrow) * 32 + lhi * 8);
    }

    f32x4 o0[2], o1[2];
    float lsum[2];
    #pragma unroll
    for (int qi = 0; qi < 2; qi++) {
        o0[qi] = (f32x4){0.f, 0.f, 0.f, 0.f};
        o1[qi] = (f32x4){0.f, 0.f, 0.f, 0.f};
        lsum[qi] = 0.f;
    }

    // K staging: pre-swizzled global source, linear LDS dest (gload_lds ok:
    // dest = base + tid*16B = wave-uniform base + lane*16)
    const int krow = tid >> 2, kcp = tid & 3;
    const int kclog = kcp ^ ((krow >> 1) & 3);
    const unsigned short* kg = Kbf + ((size_t)bh * MP + krow) * 32 + kclog * 8;
    const int kloff = tid * 8;
    // V staging: linear global read, permuted+swizzled LDS scatter (2x b64)
    const int vrow = tid >> 3, vc = tid & 7;
    const int vh = vc >> 2, c2 = vc & 3;
    const unsigned short* vg = Vt + ((size_t)bh * 32 + vrow) * MP + vc * 8;
    const int slotA = vh * 4 + 2 * (c2 & 1);
    const int hoff = (c2 >> 1) * 4;   // ushort offset within 16B slot
    const int v0off = vrow * 64 + ((slotA ^ (vrow & 7)) * 8) + hoff;
    const int v1off = vrow * 64 + (((slotA + 1) ^ (vrow & 7)) * 8) + hoff;

    // prologue: stage tile 0 into buffer 0 (normal syncthreads drains both
    // the K gload_lds (vmcnt) and the V ds_writes (lgkm))
    gload16(kg, &Klds[0][kloff]);
    {
        uint4 vd = *reinterpret_cast<const uint4*>(vg);
        *reinterpret_cast<uint2*>(&Vlds[0][v0off]) = make_uint2(vd.x, vd.y);
        *reinterpret_cast<uint2*>(&Vlds[0][v1off]) = make_uint2(vd.z, vd.w);
    }
    __syncthreads();

    int buf = 0;
    for (int t0 = 0; t0 < MP; t0 += 64) {
        const bool more = (t0 + 64 < MP);
        uint4 vn = {0, 0, 0, 0};
        if (more) {
            gload16(kg + (size_t)(t0 + 64) * 32, &Klds[buf ^ 1][kloff]);
            vn = *reinterpret_cast<const uint4*>(vg + (t0 + 64));
        }
        const unsigned short* Kb = Klds[buf];
        const unsigned short* Vb = Vlds[buf];
        const bool last = (t0 + 64 > M_TOK);
        #pragma unroll
        for (int hh = 0; hh < 2; hh++) {
            int tre = hh * 32 + l16;
            int tro = hh * 32 + 16 + l16;
            short8 kfe = *reinterpret_cast<const short8*>(
                Kb + tre * 32 + ((lhi ^ ((tre >> 1) & 3)) * 8));
            short8 kfo = *reinterpret_cast<const short8*>(
                Kb + tro * 32 + ((lhi ^ ((tro >> 1) & 3)) * 8));
            int rv0 = l16, rv1 = 16 + l16;
            short8 vf0 = *reinterpret_cast<const short8*>(
                Vb + rv0 * 64 + (((hh * 4 + lhi) ^ (rv0 & 7)) * 8));
            short8 vf1 = *reinterpret_cast<const short8*>(
                Vb + rv1 * 64 + (((hh * 4 + lhi) ^ (rv1 & 7)) * 8));
            #pragma unroll
            for (int qi = 0; qi < 2; qi++) {
                f32x4 Se = __builtin_amdgcn_mfma_f32_16x16x32_bf16(
                    kfe, qf[qi], (f32x4){0.f, 0.f, 0.f, 0.f}, 0, 0, 0);
                f32x4 So = __builtin_amdgcn_mfma_f32_16x16x32_bf16(
                    kfo, qf[qi], (f32x4){0.f, 0.f, 0.f, 0.f}, 0, 0, 0);
                float ee0 = EXP2(Se[0]), ee1 = EXP2(Se[1]), ee2 = EXP2(Se[2]), ee3 = EXP2(Se[3]);
                float eo0 = EXP2(So[0]), eo1 = EXP2(So[1]), eo2 = EXP2(So[2]), eo3 = EXP2(So[3]);
                if (!last) {
                    lsum[qi] += ((ee0 + ee1) + (ee2 + ee3)) + ((eo0 + eo1) + (eo2 + eo3));
                } else if (hh == 0) {
                    // even-sub tokens 768+lhi*4+r all valid; odd-sub only token 784
                    lsum[qi] += (ee0 + ee1) + (ee2 + ee3);
                    if (lhi == 0) lsum[qi] += eo0;
                }
                union { short8 s; unsigned int u[4]; } pf;
                asm("v_cvt_pk_bf16_f32 %0, %1, %2" : "=v"(pf.u[0]) : "v"(ee0), "v"(ee1));
                asm("v_cvt_pk_bf16_f32 %0, %1, %2" : "=v"(pf.u[1]) : "v"(ee2), "v"(ee3));
                asm("v_cvt_pk_bf16_f32 %0, %1, %2" : "=v"(pf.u[2]) : "v"(eo0), "v"(eo1));
                asm("v_cvt_pk_bf16_f32 %0, %1, %2" : "=v"(pf.u[3]) : "v"(eo2), "v"(eo3));
                o0[qi] = __builtin_amdgcn_mfma_f32_16x16x32_bf16(pf.s, vf0, o0[qi], 0, 0, 0);
                o1[qi] = __builtin_amdgcn_mfma_f32_16x16x32_bf16(pf.s, vf1, o1[qi], 0, 0, 0);
            }
        }
        if (more) {
            // drain t+1 loads (hidden under the compute above), then write V
            asm volatile("s_waitcnt vmcnt(0)" ::: "memory");
            *reinterpret_cast<uint2*>(&Vlds[buf ^ 1][v0off]) = make_uint2(vn.x, vn.y);
            *reinterpret_cast<uint2*>(&Vlds[buf ^ 1][v1off]) = make_uint2(vn.z, vn.w);
            buf ^= 1;
        }
        // raw barrier WITHOUT compiler vmcnt drain; lgkm drains ds writes.
        // single asm = full fence both sides (rule #18).
        asm volatile("s_waitcnt lgkmcnt(0)\n\ts_barrier" ::: "memory");
    }
    // total row-sum: reduce across lhi groups; lane l16=r holds row r's total
    #pragma unroll
    for (int qi = 0; qi < 2; qi++) {
        lsum[qi] += __shfl_xor(lsum[qi], 16);
        lsum[qi] += __shfl_xor(lsum[qi], 32);
    }
    #pragma unroll
    for (int qi = 0; qi < 2; qi++) {
        #pragma unroll
        for (int r = 0; r < 4; r++) {
            int qrw = lhi * 4 + r;
            float inv = 1.f / __shfl(lsum[qi], qrw);   // unconditional, r4-style
            int row = q0 + qi * 16 + qrw;
            if (row < N_TOK) {
                unsigned short* op = AObf + ((size_t)(b * N_TOK + row)) * 256 + h * 32;
                op[l16]      = f2bf(o0[qi][r] * inv);
                op[16 + l16] = f2bf(o1[qi][r] * inv);
            }
        }
    }
}

// ---------------------------------------------------------------------------
extern "C" void kernel_launch(void* const* d_in, const int* in_sizes, int n_in,
                              void* d_out, int out_size, void* d_ws, size_t ws_size,
                              hipStream_t stream) {
    const float* x      = (const float*)d_in[0];
    const float* Wq     = (const float*)d_in[1];
    const float* Wkv    = (const float*)d_in[2];
    const float* conv_w = (const float*)d_in[3];
    const float* Wproj  = (const float*)d_in[4];
    const float* bproj  = (const float*)d_in[5];
    float* out = (float*)d_out;

    unsigned short* us   = (unsigned short*)d_ws;
    unsigned short* xb   = us;                     // 6424576
    unsigned short* AObf = us;                     // alias of xb (xb dead by attn)
    unsigned short* Qbf  = xb + 6424576;           // 6424576
    unsigned short* Kbf  = Qbf + 6424576;          // 1703936
    unsigned short* Vtb  = Kbf + 1703936;          // 1703936 (contiguous after Kbf)
    unsigned short* XRb  = Vtb + 1703936;          // 1607680
    unsigned short* Wqt  = XRb + 1607680;          // 65536
    unsigned short* Wkvt = Wqt + 65536;            // 131072
    unsigned short* W2t  = Wkvt + 131072;          // 262144
    unsigned short* Wpt  = W2t + 262144;           // 65536
    float* XRf  = (float*)(Wpt + 65536);           // 1607680 f
    float* psum = XRf + 1607680;                   // 57344
    float* psq  = psum + 57344;                    // 57344
    float* mean = psq + 57344;                     // 2048
    float* rstd = mean + 2048;                     // 2048

    prep_kernel<<<9075, 256, 0, stream>>>(x, Wq, Wkv, conv_w, Wproj,
                                          xb, Wqt, Wkvt, W2t, Wpt, Kbf, Vtb);
    mfma_gemm_kernel<256, A_PLAIN, EPI_Q><<<dim3(393, 4), 256, 0, stream>>>(
        xb, Wqt, Qbf, nullptr, B * N_TOK);
    mfma_gemm_kernel<1024, A_CONV, EPI_XR><<<dim3(98, 4), 256, 0, stream>>>(
        xb, W2t, XRf, nullptr, B * 784);
    stats_partial_kernel<<<B * 28, 256, 0, stream>>>(XRf, psum, psq);
    stats_final_kernel<<<B, 256, 0, stream>>>(psum, psq, mean, rstd);
    normalize_kernel<<<6280, 256, 0, stream>>>(mean, rstd, XRf, XRb, xb);
    mfma_gemm_kernel<256, A_PLAIN, EPI_KV><<<dim3(99, 8), 256, 0, stream>>>(
        XRb, Wkvt, Kbf, nullptr, B * M_TOK);
    attn_mfma_kernel<<<dim3(25, 8, 8), 256, 0, stream>>>(Qbf, Kbf, Vtb, AObf);
    mfma_gemm_kernel<256, A_PLAIN, EPI_OUT><<<dim3(393, 4), 256, 0, stream>>>(
        AObf, Wpt, out, bproj, B * N_TOK);
}

// Round 13
// 116.506 us; speedup vs baseline: 1.0419x; 1.0314x over previous
//
#include <hip/hip_runtime.h>
#include <math.h>

#define B 8
#define N_TOK 3137
#define D 256
#define H 8
#define DH 32
#define NX 56
#define M_SR 784     // 28*28
#define M_TOK 785    // 1 cls + 784
#define MP 832       // padded token count (13 * 64)
// dh^-0.5 * log2(e): exp(s) = exp2(s * log2e), folded into Q scale
#define QSCALE 0.25503486f
#define EPS 1e-5f

typedef __attribute__((ext_vector_type(8))) short short8;
typedef __attribute__((ext_vector_type(4))) float f32x4;

#if __has_builtin(__builtin_amdgcn_exp2f)
#define EXP2(x) __builtin_amdgcn_exp2f(x)
#else
#define EXP2(x) exp2f(x)
#endif

static __device__ __forceinline__ unsigned short f2bf(float f) {
    unsigned int u = __float_as_uint(f);
    u += 0x7fffu + ((u >> 16) & 1u);
    return (unsigned short)(u >> 16);
}

// async global->LDS 16B (m97 ladder step-3 pattern)
static __device__ __forceinline__ void gload16(const unsigned short* g, unsigned short* l) {
    __builtin_amdgcn_global_load_lds(
        (const __attribute__((address_space(1))) unsigned int*)g,
        (__attribute__((address_space(3))) unsigned int*)l,
        16, 0, 0);
}

// ---------------------------------------------------------------------------
// Fused prep: x->bf16, 4 weight transposes, K/V pad zeroing. One launch.
__global__ void prep_kernel(const float* __restrict__ x, const float* __restrict__ Wq,
                            const float* __restrict__ Wkv, const float* __restrict__ cw,
                            const float* __restrict__ Wproj,
                            unsigned short* __restrict__ xb, unsigned short* __restrict__ Wqt,
                            unsigned short* __restrict__ Wkvt, unsigned short* __restrict__ W2t,
                            unsigned short* __restrict__ Wpt,
                            unsigned short* __restrict__ Kbf, unsigned short* __restrict__ Vtb) {
    int bid = blockIdx.x, tid = threadIdx.x;
    if (bid < 6274) {                       // x fp32 -> bf16, float4-vectorized
        int idx = bid * 256 + tid;
        float4 v = ((const float4*)x)[idx];
        ushort4 o; o.x = f2bf(v.x); o.y = f2bf(v.y); o.z = f2bf(v.z); o.w = f2bf(v.w);
        ((ushort4*)xb)[idx] = o;
    } else if (bid < 6530) {                // Wq [256][256] -> Wqt [n][k]
        int idx = (bid - 6274) * 256 + tid;
        int n = idx & 255, k = idx >> 8;
        Wqt[n * 256 + k] = f2bf(Wq[idx]);
    } else if (bid < 7042) {                // Wkv [256][512] -> Wkvt [n][k]
        int idx = (bid - 6530) * 256 + tid;
        int n = idx & 511, k = idx >> 9;
        Wkvt[(size_t)n * 256 + k] = f2bf(Wkv[idx]);
    } else if (bid < 8066) {                // conv_w [O][I][2][2] -> W2t [o][q*256+i]
        int idx = (bid - 7042) * 256 + tid;
        int o = idx >> 10, k = idx & 1023;
        int q = k >> 8, i = k & 255;
        W2t[idx] = f2bf(cw[((size_t)o << 10) + (i << 2) + q]);
    } else if (bid < 8322) {                // Wproj -> Wpt
        int idx = (bid - 8066) * 256 + tid;
        int n = idx & 255, k = idx >> 8;
        Wpt[n * 256 + k] = f2bf(Wproj[idx]);
    } else {                                // zero pad rows m=785..831 of Kbf, Vtb
        int idx = (bid - 8322) * 256 + tid;
        if (idx < 96256) {
            int d = idx & 31; int rest = idx >> 5;
            int m = M_TOK + rest % 47; int bh = rest / 47;
            Kbf[((size_t)bh * MP + m) * 32 + d] = 0;
        } else if (idx < 192512) {
            int i2 = idx - 96256;
            int j = i2 % 47; int rest = i2 / 47;
            int d = rest & 31; int bh = rest >> 5;
            Vtb[((size_t)bh * 32 + d) * MP + M_TOK + j] = 0;
        }
    }
}

// ---------------------------------------------------------------------------
// bf16 MFMA GEMM: C[M][N] = A[M][KTOT] x Bt[N][KTOT]^T, fused epilogues.
// BK=128 K-chunks: 16KB+16KB LDS -> 5 blocks/CU. Staging via global_load_lds
// width-16: linear LDS dest, inverse-swizzled per-lane global source.
enum EpiMode { EPI_Q, EPI_XR, EPI_KV, EPI_OUT };
enum AMode { A_PLAIN, A_CONV };

template<int KTOT, AMode AM, EpiMode EM>
__global__ __launch_bounds__(256) void mfma_gemm_kernel(
        const unsigned short* __restrict__ A,
        const unsigned short* __restrict__ Bt,
        void* __restrict__ Cout,
        const float* __restrict__ bias,
        int Mrows) {
    __shared__ __align__(16) unsigned short Alds[64 * 128];
    __shared__ __align__(16) unsigned short Blds[64 * 128];
    const int tid = threadIdx.x;
    const int lane = tid & 63, wave = tid >> 6;
    const int l16 = lane & 15, lhi = lane >> 4;
    const int row0 = blockIdx.x * 64;
    const int col0 = blockIdx.y * 64;
    const int wr = (wave >> 1) * 32, wc = (wave & 1) * 32;

    f32x4 acc[2][2];
    #pragma unroll
    for (int mi = 0; mi < 2; mi++)
        #pragma unroll
        for (int ni = 0; ni < 2; ni++)
            acc[mi][ni] = (f32x4){0.f, 0.f, 0.f, 0.f};

    for (int kc = 0; kc < KTOT / 128; kc++) {
        __syncthreads();
        // stage A: linear LDS dest (r,p), fetch logical slot s = p ^ (r&7)
        #pragma unroll
        for (int j = 0; j < 4; j++) {
            int sl = j * 256 + tid;
            int r = sl >> 4, p = sl & 15;
            int s = p ^ (r & 7);
            const unsigned short* gp;
            if (AM == A_PLAIN) {
                gp = A + ((size_t)(row0 + r) * KTOT + kc * 128 + s * 8);
            } else {
                int grow = row0 + r;
                int b = grow / 784, pp = grow - b * 784;
                int oy = pp / 28, ox = pp - oy * 28;
                int q = kc >> 1;
                int kh = q >> 1, kw = q & 1;
                int tok = 1 + (2 * oy + kh) * NX + (2 * ox + kw);
                gp = A + ((size_t)(b * N_TOK + tok) * 256 + (kc & 1) * 128 + s * 8);
            }
            gload16(gp, &Alds[r * 128 + p * 8]);
        }
        // stage Bt (rows col0..col0+63 always in-bounds)
        #pragma unroll
        for (int j = 0; j < 4; j++) {
            int sl = j * 256 + tid;
            int r = sl >> 4, p = sl & 15;
            int s = p ^ (r & 7);
            gload16(Bt + ((size_t)(col0 + r) * KTOT + kc * 128 + s * 8),
                    &Blds[r * 128 + p * 8]);
        }
        __syncthreads();
        #pragma unroll
        for (int ks = 0; ks < 4; ks++) {
            short8 af[2], bfr[2];
            #pragma unroll
            for (int mi = 0; mi < 2; mi++) {
                int r = wr + mi * 16 + l16;
                int s = ks * 4 + lhi;
                af[mi] = *reinterpret_cast<const short8*>(Alds + r * 128 + ((s ^ (r & 7)) * 8));
            }
            #pragma unroll
            for (int ni = 0; ni < 2; ni++) {
                int r = wc + ni * 16 + l16;
                int s = ks * 4 + lhi;
                bfr[ni] = *reinterpret_cast<const short8*>(Blds + r * 128 + ((s ^ (r & 7)) * 8));
            }
            #pragma unroll
            for (int mi = 0; mi < 2; mi++)
                #pragma unroll
                for (int ni = 0; ni < 2; ni++)
                    acc[mi][ni] = __builtin_amdgcn_mfma_f32_16x16x32_bf16(af[mi], bfr[ni], acc[mi][ni], 0, 0, 0);
        }
    }

    #pragma unroll
    for (int mi = 0; mi < 2; mi++) {
        #pragma unroll
        for (int ni = 0; ni < 2; ni++) {
            #pragma unroll
            for (int r = 0; r < 4; r++) {
                int grow = row0 + wr + mi * 16 + lhi * 4 + r;
                int gcol = col0 + wc + ni * 16 + l16;
                float v = acc[mi][ni][r];
                if (EM == EPI_Q) {
                    if (grow < Mrows) {
                        int b = grow / N_TOK, n = grow - b * N_TOK;
                        int h = gcol >> 5, d = gcol & 31;
                        ((unsigned short*)Cout)[(((size_t)(b * 8 + h) * N_TOK + n) * 32) + d] = f2bf(v * QSCALE);
                    }
                } else if (EM == EPI_XR) {
                    int b = grow / 784, p = grow - b * 784;
                    ((float*)Cout)[((size_t)(b * M_TOK) + 1 + p) * 256 + gcol] = v;
                } else if (EM == EPI_KV) {
                    if (grow < Mrows) {
                        int b = grow / M_TOK, m = grow - b * M_TOK;
                        if (gcol < 256) {
                            int h = gcol >> 5, d = gcol & 31;
                            ((unsigned short*)Cout)[((size_t)(b * 8 + h) * MP + m) * 32 + d] = f2bf(v);
                        } else {
                            int c = gcol - 256;
                            int h = c >> 5, d = c & 31;
                            ((unsigned short*)Cout)[(size_t)64 * MP * 32 + ((size_t)(b * 8 + h) * 32 + d) * MP + m] = f2bf(v);
                        }
                    }
                } else { // EPI_OUT
                    if (grow < Mrows)
                        ((float*)Cout)[(size_t)grow * 256 + gcol] = v + bias[gcol];
                }
            }
        }
    }
}

// ---------------------------------------------------------------------------
// Instance-norm (deterministic 3-stage) on fp32 XRf, rows 1..784
__global__ void stats_partial_kernel(const float* __restrict__ XR,
                                     float* __restrict__ psum, float* __restrict__ psq) {
    int b = blockIdx.x / 28, pg = blockIdx.x % 28;
    int c = threadIdx.x;
    float s = 0.f, s2 = 0.f;
    for (int pp = 0; pp < 28; pp++) {
        int p = pg * 28 + pp;
        float v = XR[((size_t)b * M_TOK + 1 + p) * D + c];
        s += v; s2 += v * v;
    }
    psum[(size_t)(b * 28 + pg) * D + c] = s;
    psq [(size_t)(b * 28 + pg) * D + c] = s2;
}

__global__ void stats_final_kernel(const float* __restrict__ psum, const float* __restrict__ psq,
                                   float* __restrict__ mean, float* __restrict__ rstd) {
    int b = blockIdx.x, c = threadIdx.x;
    float s = 0.f, s2 = 0.f;
    for (int pg = 0; pg < 28; pg++) {
        s  += psum[(size_t)(b * 28 + pg) * D + c];
        s2 += psq [(size_t)(b * 28 + pg) * D + c];
    }
    float mu = s * (1.f / 784.f);
    float var = s2 * (1.f / 784.f) - mu * mu;
    mean[b * D + c] = mu;
    rstd[b * D + c] = rsqrtf(var + EPS);
}

// normalize rows 1..784 -> XRb bf16; blocks >= 6272 copy the cls row from xb
__global__ void normalize_kernel(const float* __restrict__ mean, const float* __restrict__ rstd,
                                 const float* __restrict__ XRf, unsigned short* __restrict__ XRb,
                                 const unsigned short* __restrict__ xb) {
    int bid = blockIdx.x;
    if (bid < 6272) {
        int idx = bid * 256 + threadIdx.x;
        int c = idx & 255;
        int bp = idx >> 8;
        int b = bp / 784, p = bp - b * 784;
        size_t off = ((size_t)b * M_TOK + 1 + p) * 256 + c;
        XRb[off] = f2bf((XRf[off] - mean[b * 256 + c]) * rstd[b * 256 + c]);
    } else {
        int b = bid - 6272, c = threadIdx.x;
        XRb[(size_t)b * M_TOK * 256 + c] = xb[(size_t)b * N_TOK * 256 + c];
    }
}

// ---------------------------------------------------------------------------
// Swapped-operand MFMA flash attention — r9-EXACT math/staging (proven
// 44.5us, absmax 4.9e-4), with ONLY the launch geometry changed: 1D grid of
// 1600 blocks + bijective XCD swizzle (1600%8==0) so each XCD's contiguous
// 200-block chunk covers 8 complete (b,h) pairs -> K/V (850KB) and Q (1.6MB)
// become L2-resident per XCD, cutting HBM-miss latency on the K/V path.
__global__ __launch_bounds__(256) void attn_mfma_kernel(
        const unsigned short* __restrict__ Qbf,
        const unsigned short* __restrict__ Kbf,
        const unsigned short* __restrict__ Vt,
        unsigned short* __restrict__ AObf) {
    __shared__ __align__(16) unsigned short Klds[64 * 32];
    __shared__ __align__(16) unsigned short Vlds[32 * 64];
    const int tid = threadIdx.x;
    const int lane = tid & 63, wave = tid >> 6;
    const int l16 = lane & 15, lhi = lane >> 4;
    // XCD swizzle: xcd = bid&7 gets sid range [xcd*200, xcd*200+200)
    const int sid = (blockIdx.x & 7) * 200 + (blockIdx.x >> 3);
    const int xq = sid % 25;
    const int bh = sid / 25;
    const int b = bh >> 3, h = bh & 7;
    const int q0 = xq * 128 + wave * 32;

    short8 qf[2];
    #pragma unroll
    for (int qi = 0; qi < 2; qi++) {
        qf[qi] = (short8){0, 0, 0, 0, 0, 0, 0, 0};
        int qrow = q0 + qi * 16 + l16;
        if (qrow < N_TOK)
            qf[qi] = *reinterpret_cast<const short8*>(Qbf + ((size_t)bh * N_TOK + qrow) * 32 + lhi * 8);
    }

    f32x4 o0[2], o1[2];
    float lsum[2];
    #pragma unroll
    for (int qi = 0; qi < 2; qi++) {
        o0[qi] = (f32x4){0.f, 0.f, 0.f, 0.f};
        o1[qi] = (f32x4){0.f, 0.f, 0.f, 0.f};
        lsum[qi] = 0.f;
    }

    // K staging: pre-swizzled global source, linear LDS dest
    const int krow = tid >> 2, kcp = tid & 3;
    const int kclog = kcp ^ ((krow >> 1) & 3);
    const unsigned short* kg = Kbf + ((size_t)bh * MP + krow) * 32 + kclog * 8;
    unsigned short* kl = Klds + tid * 8;
    // V staging: linear global read, permuted+swizzled LDS scatter (2x b64)
    const int vrow = tid >> 3, vc = tid & 7;
    const int vh = vc >> 2, c2 = vc & 3;
    const unsigned short* vg = Vt + ((size_t)bh * 32 + vrow) * MP + vc * 8;
    const int slotA = vh * 4 + 2 * (c2 & 1);
    const int hoff = (c2 >> 1) * 4;   // ushort offset within 16B slot
    unsigned short* vl0 = Vlds + vrow * 64 + ((slotA ^ (vrow & 7)) * 8) + hoff;
    unsigned short* vl1 = Vlds + vrow * 64 + (((slotA + 1) ^ (vrow & 7)) * 8) + hoff;

    for (int t0 = 0; t0 < MP; t0 += 64) {
        __syncthreads();
        uint4 kd = *reinterpret_cast<const uint4*>(kg + (size_t)t0 * 32);
        uint4 vd = *reinterpret_cast<const uint4*>(vg + t0);
        *reinterpret_cast<uint4*>(kl) = kd;
        *reinterpret_cast<uint2*>(vl0) = make_uint2(vd.x, vd.y);
        *reinterpret_cast<uint2*>(vl1) = make_uint2(vd.z, vd.w);
        __syncthreads();
        const bool last = (t0 + 64 > M_TOK);
        #pragma unroll
        for (int hh = 0; hh < 2; hh++) {
            int tre = hh * 32 + l16;
            int tro = hh * 32 + 16 + l16;
            short8 kfe = *reinterpret_cast<const short8*>(
                Klds + tre * 32 + ((lhi ^ ((tre >> 1) & 3)) * 8));
            short8 kfo = *reinterpret_cast<const short8*>(
                Klds + tro * 32 + ((lhi ^ ((tro >> 1) & 3)) * 8));
            int rv0 = l16, rv1 = 16 + l16;
            short8 vf0 = *reinterpret_cast<const short8*>(
                Vlds + rv0 * 64 + (((hh * 4 + lhi) ^ (rv0 & 7)) * 8));
            short8 vf1 = *reinterpret_cast<const short8*>(
                Vlds + rv1 * 64 + (((hh * 4 + lhi) ^ (rv1 & 7)) * 8));
            #pragma unroll
            for (int qi = 0; qi < 2; qi++) {
                f32x4 Se = __builtin_amdgcn_mfma_f32_16x16x32_bf16(
                    kfe, qf[qi], (f32x4){0.f, 0.f, 0.f, 0.f}, 0, 0, 0);
                f32x4 So = __builtin_amdgcn_mfma_f32_16x16x32_bf16(
                    kfo, qf[qi], (f32x4){0.f, 0.f, 0.f, 0.f}, 0, 0, 0);
                float ee0 = EXP2(Se[0]), ee1 = EXP2(Se[1]), ee2 = EXP2(Se[2]), ee3 = EXP2(Se[3]);
                float eo0 = EXP2(So[0]), eo1 = EXP2(So[1]), eo2 = EXP2(So[2]), eo3 = EXP2(So[3]);
                if (!last) {
                    lsum[qi] += ((ee0 + ee1) + (ee2 + ee3)) + ((eo0 + eo1) + (eo2 + eo3));
                } else if (hh == 0) {
                    // even-sub tokens 768+lhi*4+r all valid; odd-sub only token 784
                    lsum[qi] += (ee0 + ee1) + (ee2 + ee3);
                    if (lhi == 0) lsum[qi] += eo0;
                }
                union { short8 s; unsigned int u[4]; } pf;
                asm("v_cvt_pk_bf16_f32 %0, %1, %2" : "=v"(pf.u[0]) : "v"(ee0), "v"(ee1));
                asm("v_cvt_pk_bf16_f32 %0, %1, %2" : "=v"(pf.u[1]) : "v"(ee2), "v"(ee3));
                asm("v_cvt_pk_bf16_f32 %0, %1, %2" : "=v"(pf.u[2]) : "v"(eo0), "v"(eo1));
                asm("v_cvt_pk_bf16_f32 %0, %1, %2" : "=v"(pf.u[3]) : "v"(eo2), "v"(eo3));
                o0[qi] = __builtin_amdgcn_mfma_f32_16x16x32_bf16(pf.s, vf0, o0[qi], 0, 0, 0);
                o1[qi] = __builtin_amdgcn_mfma_f32_16x16x32_bf16(pf.s, vf1, o1[qi], 0, 0, 0);
            }
        }
    }
    // total row-sum: reduce across lhi groups; lane l16=r holds row r's total
    #pragma unroll
    for (int qi = 0; qi < 2; qi++) {
        lsum[qi] += __shfl_xor(lsum[qi], 16);
        lsum[qi] += __shfl_xor(lsum[qi], 32);
    }
    #pragma unroll
    for (int qi = 0; qi < 2; qi++) {
        #pragma unroll
        for (int r = 0; r < 4; r++) {
            int qrw = lhi * 4 + r;
            float inv = 1.f / __shfl(lsum[qi], qrw);   // unconditional, r4-style
            int row = q0 + qi * 16 + qrw;
            if (row < N_TOK) {
                unsigned short* op = AObf + ((size_t)(b * N_TOK + row)) * 256 + h * 32;
                op[l16]      = f2bf(o0[qi][r] * inv);
                op[16 + l16] = f2bf(o1[qi][r] * inv);
            }
        }
    }
}

// ---------------------------------------------------------------------------
extern "C" void kernel_launch(void* const* d_in, const int* in_sizes, int n_in,
                              void* d_out, int out_size, void* d_ws, size_t ws_size,
                              hipStream_t stream) {
    const float* x      = (const float*)d_in[0];
    const float* Wq     = (const float*)d_in[1];
    const float* Wkv    = (const float*)d_in[2];
    const float* conv_w = (const float*)d_in[3];
    const float* Wproj  = (const float*)d_in[4];
    const float* bproj  = (const float*)d_in[5];
    float* out = (float*)d_out;

    unsigned short* us   = (unsigned short*)d_ws;
    unsigned short* xb   = us;                     // 6424576
    unsigned short* AObf = us;                     // alias of xb (xb dead by attn)
    unsigned short* Qbf  = xb + 6424576;           // 6424576
    unsigned short* Kbf  = Qbf + 6424576;          // 1703936
    unsigned short* Vtb  = Kbf + 1703936;          // 1703936 (contiguous after Kbf)
    unsigned short* XRb  = Vtb + 1703936;          // 1607680
    unsigned short* Wqt  = XRb + 1607680;          // 65536
    unsigned short* Wkvt = Wqt + 65536;            // 131072
    unsigned short* W2t  = Wkvt + 131072;          // 262144
    unsigned short* Wpt  = W2t + 262144;           // 65536
    float* XRf  = (float*)(Wpt + 65536);           // 1607680 f
    float* psum = XRf + 1607680;                   // 57344
    float* psq  = psum + 57344;                    // 57344
    float* mean = psq + 57344;                     // 2048
    float* rstd = mean + 2048;                     // 2048

    prep_kernel<<<9075, 256, 0, stream>>>(x, Wq, Wkv, conv_w, Wproj,
                                          xb, Wqt, Wkvt, W2t, Wpt, Kbf, Vtb);
    mfma_gemm_kernel<256, A_PLAIN, EPI_Q><<<dim3(393, 4), 256, 0, stream>>>(
        xb, Wqt, Qbf, nullptr, B * N_TOK);
    mfma_gemm_kernel<1024, A_CONV, EPI_XR><<<dim3(98, 4), 256, 0, stream>>>(
        xb, W2t, XRf, nullptr, B * 784);
    stats_partial_kernel<<<B * 28, 256, 0, stream>>>(XRf, psum, psq);
    stats_final_kernel<<<B, 256, 0, stream>>>(psum, psq, mean, rstd);
    normalize_kernel<<<6280, 256, 0, stream>>>(mean, rstd, XRf, XRb, xb);
    mfma_gemm_kernel<256, A_PLAIN, EPI_KV><<<dim3(99, 8), 256, 0, stream>>>(
        XRb, Wkvt, Kbf, nullptr, B * M_TOK);
    attn_mfma_kernel<<<1600, 256, 0, stream>>>(Qbf, Kbf, Vtb, AObf);
    mfma_gemm_kernel<256, A_PLAIN, EPI_OUT><<<dim3(393, 4), 256, 0, stream>>>(
        AObf, Wpt, out, bproj, B * N_TOK);
}